// Round 11
// baseline (333.044 us; speedup 1.0000x reference)
//
#include <hip/hip_runtime.h>
#include <hip/hip_bf16.h>
#include <stdint.h>

#define B_DIM 4096
#define P_DIMC 1024
#define H_DIMC 2048
#define X_DIMC 1024
#define K_DIM 4096   // P + H + X
#define N_DIM 8192   // 4*H, packed: n = (h>>5)*128 + gate*32 + (h&31)

#define BM 256
#define BN 256
#define BK 32
#define NT (K_DIM / BK)   // 128 K-tiles

typedef __attribute__((ext_vector_type(8))) short bf16x8;
typedef __attribute__((ext_vector_type(16))) float f32x16;

template <int V> struct Int { static constexpr int value = V; };

__device__ __forceinline__ unsigned short f2bf(float f) {
  union { float f; unsigned u; } v; v.f = f;
  unsigned u = v.u;
  u += 0x7FFFu + ((u >> 16) & 1u);   // round-to-nearest-even
  return (unsigned short)(u >> 16);
}

__device__ __forceinline__ float sigm(float x) { return 1.f / (1.f + __expf(-x)); }
__device__ __forceinline__ float tanh_fast(float x) {
  float e = __expf(2.f * x);
  return 1.f - 2.f / (e + 1.f);      // safe at +/- inf
}

__device__ __forceinline__ void gl_lds16(const void* g, void* l) {
  __builtin_amdgcn_global_load_lds((const __attribute__((address_space(1))) void*)g,
                                   (__attribute__((address_space(3))) void*)l, 16, 0, 0);
}

// ---------------- pack A = [P | hidden | ext] -> bf16 [B][K] ----------------
__global__ void pack_a_kernel(const float* __restrict__ P, const float* __restrict__ Hd,
                              const float* __restrict__ X, unsigned short* __restrict__ A) {
  const int total = B_DIM * (K_DIM / 4);
  for (int idx = blockIdx.x * blockDim.x + threadIdx.x; idx < total;
       idx += gridDim.x * blockDim.x) {
    int row = idx >> 10;
    int col = (idx & 1023) << 2;
    const float* src; int off;
    if (col < P_DIMC)                { src = P;  off = row * P_DIMC + col; }
    else if (col < P_DIMC + H_DIMC)  { src = Hd; off = row * H_DIMC + (col - P_DIMC); }
    else                             { src = X;  off = row * X_DIMC + (col - P_DIMC - H_DIMC); }
    float4 v = *(const float4*)(src + off);
    ushort4 o;
    o.x = f2bf(v.x); o.y = f2bf(v.y); o.z = f2bf(v.z); o.w = f2bf(v.w);
    *(ushort4*)(A + (size_t)row * K_DIM + col) = o;
  }
}

// ------- pack Wbig [N][K] bf16, gate-minor at 32 granularity ----------------
// row n holds gate=(n>>5)&3, h=(n>>7)*32 + (n&31)
struct WPtrs {
  const float *pi, *pf, *pg, *po;
  const float *hi, *hf, *hg, *ho;
  const float *xi, *xf, *xg, *xo;
};

__global__ void pack_w_kernel(WPtrs w, unsigned short* __restrict__ Wo) {
  const int total = N_DIM * (K_DIM / 4);
  for (int idx = blockIdx.x * blockDim.x + threadIdx.x; idx < total;
       idx += gridDim.x * blockDim.x) {
    int n = idx >> 10;
    int col = (idx & 1023) << 2;
    int gate = (n >> 5) & 3;
    int h = (n >> 7) * 32 + (n & 31);
    const float* src; int off;
    if (col < P_DIMC) {
      src = gate == 0 ? w.pi : gate == 1 ? w.pf : gate == 2 ? w.pg : w.po;
      off = h * P_DIMC + col;
    } else if (col < P_DIMC + H_DIMC) {
      src = gate == 0 ? w.hi : gate == 1 ? w.hf : gate == 2 ? w.hg : w.ho;
      off = h * H_DIMC + (col - P_DIMC);
    } else {
      src = gate == 0 ? w.xi : gate == 1 ? w.xf : gate == 2 ? w.xg : w.xo;
      off = h * X_DIMC + (col - P_DIMC - H_DIMC);
    }
    float4 v = *(const float4*)(src + off);
    ushort4 o;
    o.x = f2bf(v.x); o.y = f2bf(v.y); o.z = f2bf(v.z); o.w = f2bf(v.w);
    *(ushort4*)(Wo + (size_t)n * K_DIM + col) = o;
  }
}

// ------ fused GEMM (256x256 tile, 32x32x16 MFMA, R9 schedule, ring-4) -------
// Waves 4m x 2n (wave tile 64x128); 2 k-step phases per tile; one counted
// vmcnt + one barrier per tile; compiler-counted lgkm waits (no drains).
__global__ __launch_bounds__(512, 1) void gemm_lstm_kernel(
    const unsigned short* __restrict__ A, const unsigned short* __restrict__ W,
    const float* __restrict__ cell,
    const float* __restrict__ bpi, const float* __restrict__ bpf,
    const float* __restrict__ bpg, const float* __restrict__ bpo,
    float* __restrict__ out) {
  // 4-deep tile ring: 4 * (256x32 A + 256x32 B) * 2B = 128 KiB
  __shared__ __align__(16) short As[4][BM * BK];
  __shared__ __align__(16) short Bs[4][BN * BK];

  const int T = threadIdx.x;
  const int wave = T >> 6, lane = T & 63;
  const int wm = wave >> 1, wn = wave & 1;     // 4 x 2 wave grid

  // XCD-aware mapping: 512 blocks, XCD x gets an 8x8 tile patch
  const int x = blockIdx.x & 7, local = blockIdx.x >> 3;   // local 0..63
  const int bm = (x & 1) * 8 + (local >> 3);               // 0..15
  const int bn = (x >> 1) * 8 + (local & 7);               // 0..31

  // ---- staging addressing (linear LDS dest, pre-swizzled global source) ----
  // row r (64B = 4 chunks of 16B): logical chunk c stored at slot (c+(r>>1))&3
  const int cg = ((T & 3) - (T >> 3)) & 3;     // logical chunk this thread fetches
  const int rowS = T >> 2;                     // 0..127 (inst 2: rows +128)
  const unsigned short* aG0 = A + (size_t)(bm * BM + rowS) * K_DIM + cg * 8;
  const unsigned short* aG1 = A + (size_t)(bm * BM + 128 + rowS) * K_DIM + cg * 8;
  const unsigned short* bG0 = W + (size_t)(bn * BN + rowS) * K_DIM + cg * 8;
  const unsigned short* bG1 = W + (size_t)(bn * BN + 128 + rowS) * K_DIM + cg * 8;
  const int dstOff = T * 8;                    // shorts; +4096 for rows 128-255

  // ---- fragment read offsets (32x32x16: row=lane&31, k=(lane>>5)*8) ----
  const int l31 = lane & 31, khalf = lane >> 5;
  int offA[2][2], offB[4][2];
#pragma unroll
  for (int mf = 0; mf < 2; ++mf)
#pragma unroll
    for (int ks = 0; ks < 2; ++ks)
      offA[mf][ks] = (wm * 64 + mf * 32 + l31) * BK +
                     (((ks * 2 + khalf) + (l31 >> 1)) & 3) * 8;
#pragma unroll
  for (int nf = 0; nf < 4; ++nf)
#pragma unroll
    for (int ks = 0; ks < 2; ++ks)
      offB[nf][ks] = (wn * 128 + nf * 32 + l31) * BK +
                     (((ks * 2 + khalf) + (l31 >> 1)) & 3) * 8;

  f32x16 acc[2][4] = {};

  // ---- prologue: stage tiles 0,1,2 (12 insts), wait tile 0 (vmcnt 8) ----
#pragma unroll
  for (int u = 0; u < 3; ++u) {
    short* dA = &As[u][0];
    short* dB = &Bs[u][0];
    const int kt = u * BK;
    gl_lds16(aG0 + kt, dA + dstOff);
    gl_lds16(aG1 + kt, dA + 4096 + dstOff);
    gl_lds16(bG0 + kt, dB + dstOff);
    gl_lds16(bG1 + kt, dB + 4096 + dstOff);
  }
  asm volatile("s_waitcnt vmcnt(8)" ::: "memory");
  __builtin_amdgcn_s_barrier();

  // K-loop templated on compile-time k-step stagger (KF = 0 or 1)
  auto run_loop = [&](auto kfc) {
    constexpr int KF = decltype(kfc)::value;
    constexpr int KS = 1 - KF;
    for (int t = 0; t < NT; ++t) {
      const short* bufA = &As[t & 3][0];
      const short* bufB = &Bs[t & 3][0];
      const int kt = (t + 3) * BK;
      short* dA = &As[(t + 3) & 3][0];
      short* dB = &Bs[(t + 3) & 3][0];
      bf16x8 av[2], bv[4];

      // ---- phase 0: k-step KF reads, stage A(t+3), 8 MFMA ----
#pragma unroll
      for (int i = 0; i < 2; ++i) av[i] = *(const bf16x8*)(bufA + offA[i][KF]);
#pragma unroll
      for (int j = 0; j < 4; ++j) bv[j] = *(const bf16x8*)(bufB + offB[j][KF]);
      if (t < NT - 3) {
        gl_lds16(aG0 + kt, dA + dstOff);
        gl_lds16(aG1 + kt, dA + 4096 + dstOff);
      }
      __builtin_amdgcn_s_setprio(1);
#pragma unroll
      for (int mi = 0; mi < 2; ++mi)
#pragma unroll
        for (int ni = 0; ni < 4; ++ni)
          acc[mi][ni] =
              __builtin_amdgcn_mfma_f32_32x32x16_bf16(av[mi], bv[ni], acc[mi][ni], 0, 0, 0);
      __builtin_amdgcn_s_setprio(0);
      __builtin_amdgcn_sched_barrier(0);   // phase boundary

      // ---- phase 1: k-step KS reads, stage B(t+3), 8 MFMA ----
#pragma unroll
      for (int i = 0; i < 2; ++i) av[i] = *(const bf16x8*)(bufA + offA[i][KS]);
#pragma unroll
      for (int j = 0; j < 4; ++j) bv[j] = *(const bf16x8*)(bufB + offB[j][KS]);
      if (t < NT - 3) {
        gl_lds16(bG0 + kt, dB + dstOff);
        gl_lds16(bG1 + kt, dB + 4096 + dstOff);
      }
      __builtin_amdgcn_s_setprio(1);
#pragma unroll
      for (int mi = 0; mi < 2; ++mi)
#pragma unroll
        for (int ni = 0; ni < 4; ++ni)
          acc[mi][ni] =
              __builtin_amdgcn_mfma_f32_32x32x16_bf16(av[mi], bv[ni], acc[mi][ni], 0, 0, 0);
      __builtin_amdgcn_s_setprio(0);
      __builtin_amdgcn_sched_barrier(0);

      // counted vmcnt: tile t+1 resident; t+2/t+3 (8 insts) stay in flight
      if (t < NT - 3)       { asm volatile("s_waitcnt vmcnt(8)" ::: "memory"); }
      else if (t == NT - 3) { asm volatile("s_waitcnt vmcnt(4)" ::: "memory"); }
      else if (t == NT - 2) { asm volatile("s_waitcnt vmcnt(0)" ::: "memory"); }
      __builtin_amdgcn_s_barrier();
    }
  };
  if (wave & 1) run_loop(Int<1>{});
  else          run_loop(Int<0>{});

  // ---- fused LSTM epilogue ----
  // 32x32 C/D: col=lane&31, row=(reg&3)+8*(reg>>2)+4*(lane>>5)  [m74/m101]
  // n-frag nf = gate; h = bn*64 + wn*32 + col
  const int h = bn * 64 + wn * 32 + l31;
  const float bi = bpi[h], bf_ = bpf[h], bg = bpg[h], bo = bpo[h];
  const int rbase = bm * BM + wm * 64 + khalf * 4;
#pragma unroll
  for (int mf = 0; mf < 2; ++mf) {
#pragma unroll
    for (int reg = 0; reg < 16; ++reg) {
      const int brow = rbase + mf * 32 + (reg & 3) + 8 * (reg >> 2);
      float gi = acc[mf][0][reg] + bi;
      float gf = acc[mf][1][reg] + bf_;
      float gg = acc[mf][2][reg] + bg;
      float go = acc[mf][3][reg] + bo;
      float i_ = sigm(gi), f_ = sigm(gf), g_ = tanh_fast(gg), o_ = sigm(go);
      float cold = cell[(size_t)brow * H_DIMC + h];
      float cn = f_ * cold + i_ * g_;
      out[(size_t)brow * H_DIMC + h] = o_ * tanh_fast(cn);
      out[(size_t)B_DIM * H_DIMC + (size_t)brow * H_DIMC + h] = cn;
    }
  }
}

extern "C" void kernel_launch(void* const* d_in, const int* in_sizes, int n_in,
                              void* d_out, int out_size, void* d_ws, size_t ws_size,
                              hipStream_t stream) {
  const float* P    = (const float*)d_in[0];
  const float* Hd   = (const float*)d_in[1];
  const float* cell = (const float*)d_in[2];
  const float* X    = (const float*)d_in[3];
  WPtrs w;
  w.pi = (const float*)d_in[4];   const float* bpi = (const float*)d_in[5];
  w.pf = (const float*)d_in[6];   const float* bpf = (const float*)d_in[7];
  w.pg = (const float*)d_in[8];   const float* bpg = (const float*)d_in[9];
  w.po = (const float*)d_in[10];  const float* bpo = (const float*)d_in[11];
  w.hi = (const float*)d_in[12];  w.hf = (const float*)d_in[13];
  w.hg = (const float*)d_in[14];  w.ho = (const float*)d_in[15];
  w.xi = (const float*)d_in[16];  w.xf = (const float*)d_in[17];
  w.xg = (const float*)d_in[18];  w.xo = (const float*)d_in[19];

  unsigned short* Abf = (unsigned short*)d_ws;                 // 32 MiB
  unsigned short* Wbf = Abf + (size_t)B_DIM * K_DIM;           // 64 MiB

  pack_a_kernel<<<2048, 256, 0, stream>>>(P, Hd, X, Abf);
  pack_w_kernel<<<2048, 256, 0, stream>>>(w, Wbf);
  gemm_lstm_kernel<<<512, 512, 0, stream>>>(Abf, Wbf, cell, bpi, bpf, bpg, bpo,
                                            (float*)d_out);
}

// Round 12
// 297.078 us; speedup vs baseline: 1.1211x; 1.1211x over previous
//
#include <hip/hip_runtime.h>
#include <hip/hip_bf16.h>
#include <stdint.h>

#define B_DIM 4096
#define P_DIMC 1024
#define H_DIMC 2048
#define X_DIMC 1024
#define K_DIM 4096   // P + H + X
#define N_DIM 8192   // 4*H (gate-minor packed: n = (h>>4)*64 + gate*16 + (h&15))

#define BM 256
#define BN 256
#define BK 64
#define NT (K_DIM / BK)   // 64 K-tiles

typedef __attribute__((ext_vector_type(8))) short bf16x8;
typedef __attribute__((ext_vector_type(4))) float f32x4;

template <int V> struct Int { static constexpr int value = V; };

__device__ __forceinline__ unsigned short f2bf(float f) {
  union { float f; unsigned u; } v; v.f = f;
  unsigned u = v.u;
  u += 0x7FFFu + ((u >> 16) & 1u);   // round-to-nearest-even
  return (unsigned short)(u >> 16);
}

__device__ __forceinline__ float sigm(float x) { return 1.f / (1.f + __expf(-x)); }
__device__ __forceinline__ float tanh_fast(float x) {
  float e = __expf(2.f * x);
  return 1.f - 2.f / (e + 1.f);      // safe at +/- inf
}

__device__ __forceinline__ void gl_lds16(const void* g, void* l) {
  __builtin_amdgcn_global_load_lds((const __attribute__((address_space(1))) void*)g,
                                   (__attribute__((address_space(3))) void*)l, 16, 0, 0);
}

// ---------------- pack A = [P | hidden | ext] -> bf16 [B][K] ----------------
__global__ void pack_a_kernel(const float* __restrict__ P, const float* __restrict__ Hd,
                              const float* __restrict__ X, unsigned short* __restrict__ A) {
  const int total = B_DIM * (K_DIM / 4);
  for (int idx = blockIdx.x * blockDim.x + threadIdx.x; idx < total;
       idx += gridDim.x * blockDim.x) {
    int row = idx >> 10;
    int col = (idx & 1023) << 2;
    const float* src; int off;
    if (col < P_DIMC)                { src = P;  off = row * P_DIMC + col; }
    else if (col < P_DIMC + H_DIMC)  { src = Hd; off = row * H_DIMC + (col - P_DIMC); }
    else                             { src = X;  off = row * X_DIMC + (col - P_DIMC - H_DIMC); }
    float4 v = *(const float4*)(src + off);
    ushort4 o;
    o.x = f2bf(v.x); o.y = f2bf(v.y); o.z = f2bf(v.z); o.w = f2bf(v.w);
    *(ushort4*)(A + (size_t)row * K_DIM + col) = o;
  }
}

// ------- pack Wbig [N][K] bf16, gate-minor at 16 granularity ----------------
// row n holds weights for gate=(n>>4)&3, h=((n>>6)<<4)|(n&15)
struct WPtrs {
  const float *pi, *pf, *pg, *po;
  const float *hi, *hf, *hg, *ho;
  const float *xi, *xf, *xg, *xo;
};

__global__ void pack_w_kernel(WPtrs w, unsigned short* __restrict__ Wo) {
  const int total = N_DIM * (K_DIM / 4);
  for (int idx = blockIdx.x * blockDim.x + threadIdx.x; idx < total;
       idx += gridDim.x * blockDim.x) {
    int n = idx >> 10;
    int col = (idx & 1023) << 2;
    int gate = (n >> 4) & 3;
    int h = ((n >> 6) << 4) | (n & 15);
    const float* src; int off;
    if (col < P_DIMC) {
      src = gate == 0 ? w.pi : gate == 1 ? w.pf : gate == 2 ? w.pg : w.po;
      off = h * P_DIMC + col;
    } else if (col < P_DIMC + H_DIMC) {
      src = gate == 0 ? w.hi : gate == 1 ? w.hf : gate == 2 ? w.hg : w.ho;
      off = h * H_DIMC + (col - P_DIMC);
    } else {
      src = gate == 0 ? w.xi : gate == 1 ? w.xf : gate == 2 ? w.xg : w.xo;
      off = h * X_DIMC + (col - P_DIMC - H_DIMC);
    }
    float4 v = *(const float4*)(src + off);
    ushort4 o;
    o.x = f2bf(v.x); o.y = f2bf(v.y); o.z = f2bf(v.z); o.w = f2bf(v.w);
    *(ushort4*)(Wo + (size_t)n * K_DIM + col) = o;
  }
}

// ------ fused GEMM (256x256, BK=64, R9 schedule, ring-2, 64 barriers) -------
// Per tile: 4 SB-fenced phases {reads, [stages at p0], 16 MFMA}; all 8 stage
// insts for t+1 issue at p0 (full-tile lead); ONE vmcnt(0) + ONE barrier at
// tile end. No lgkm drains (compiler emits counted waits). 8-chunk rotation
// swizzle for 128B rows (R10-proven, 0 conflicts).
__global__ __launch_bounds__(512, 1) void gemm_lstm_kernel(
    const unsigned short* __restrict__ A, const unsigned short* __restrict__ W,
    const float* __restrict__ cell,
    const float* __restrict__ bpi, const float* __restrict__ bpf,
    const float* __restrict__ bpg, const float* __restrict__ bpo,
    float* __restrict__ out) {
  // ring-2: 2 * (256x64 A + 256x64 B) * 2B = 128 KiB
  __shared__ __align__(16) short As[2][BM * BK];
  __shared__ __align__(16) short Bs[2][BN * BK];

  const int T = threadIdx.x;
  const int wave = T >> 6, lane = T & 63;
  const int wm = wave >> 2, wn = wave & 3;     // 2 x 4 wave grid

  // XCD-aware mapping: 512 blocks, XCD x gets an 8x8 tile patch
  const int x = blockIdx.x & 7, local = blockIdx.x >> 3;   // local 0..63
  const int bm = (x & 1) * 8 + (local >> 3);               // 0..15
  const int bn = (x >> 1) * 8 + (local & 7);               // 0..31

  // ---- staging: linear LDS dest, chunk-rotated global source ----
  // row r (128B = 8 chunks of 16B): logical chunk c stored at slot (c + (r&7))&7
  const int rowS = T >> 3;                     // 0..63 (call q covers rows q*64+rowS)
  const int cg = ((T & 7) - (rowS & 7)) & 7;   // logical chunk this thread fetches
  const unsigned short* aGq[4];
  const unsigned short* bGq[4];
#pragma unroll
  for (int q = 0; q < 4; ++q) {
    aGq[q] = A + (size_t)(bm * BM + q * 64 + rowS) * K_DIM + cg * 8;
    bGq[q] = W + (size_t)(bn * BN + q * 64 + rowS) * K_DIM + cg * 8;
  }
  const int dstOff = T * 8;                    // shorts; call q adds q*4096

#define STAGE_TILE(BUF, KT)                                                   \
  _Pragma("unroll") for (int q = 0; q < 4; ++q)                               \
    gl_lds16(aGq[q] + (KT), &As[BUF][q * 4096] + dstOff);                     \
  _Pragma("unroll") for (int q = 0; q < 4; ++q)                               \
    gl_lds16(bGq[q] + (KT), &Bs[BUF][q * 4096] + dstOff);

  // ---- fragment read offsets (swizzled; chunk c = ks*4 + kgrp) ----
  const int lrow = lane & 15, kgrp = lane >> 4;
  int offA[8][2], offB[4][2];
#pragma unroll
  for (int mf = 0; mf < 8; ++mf)
#pragma unroll
    for (int ks = 0; ks < 2; ++ks)
      offA[mf][ks] = (wm * 128 + mf * 16 + lrow) * BK +
                     (((ks * 4 + kgrp) + (lrow & 7)) & 7) * 8;
#pragma unroll
  for (int nf = 0; nf < 4; ++nf)
#pragma unroll
    for (int ks = 0; ks < 2; ++ks)
      offB[nf][ks] = (wn * 64 + nf * 16 + lrow) * BK +
                     (((ks * 4 + kgrp) + (lrow & 7)) & 7) * 8;

  f32x4 acc[8][4] = {};

  // ---- prologue: stage tile 0, drain, barrier ----
  STAGE_TILE(0, 0)
  asm volatile("s_waitcnt vmcnt(0)" ::: "memory");
  __builtin_amdgcn_s_barrier();

  // K-loop templated on compile-time A-half stagger (FIRST = 0 or 4)
  auto run_loop = [&](auto firstc) {
    constexpr int F = decltype(firstc)::value;
    constexpr int S = 4 - F;
    for (int t = 0; t < NT; ++t) {
      const int cur = t & 1, nxt = cur ^ 1;
      const short* bufA = &As[cur][0];
      const short* bufB = &Bs[cur][0];
      bf16x8 av[4], bv[4];

      // ---- p0: bv(ks0) + av(F half, ks0); stage ALL of tile t+1; MFMA ----
#pragma unroll
      for (int j = 0; j < 4; ++j) bv[j] = *(const bf16x8*)(bufB + offB[j][0]);
#pragma unroll
      for (int i = 0; i < 4; ++i) av[i] = *(const bf16x8*)(bufA + offA[F + i][0]);
      if (t < NT - 1) { STAGE_TILE(nxt, (t + 1) * BK) }
      __builtin_amdgcn_s_setprio(1);
#pragma unroll
      for (int mi = 0; mi < 4; ++mi)
#pragma unroll
        for (int ni = 0; ni < 4; ++ni)
          acc[F + mi][ni] =
              __builtin_amdgcn_mfma_f32_16x16x32_bf16(av[mi], bv[ni], acc[F + mi][ni], 0, 0, 0);
      __builtin_amdgcn_s_setprio(0);
      __builtin_amdgcn_sched_barrier(0);

      // ---- p1: av(S half, ks0); MFMA ----
#pragma unroll
      for (int i = 0; i < 4; ++i) av[i] = *(const bf16x8*)(bufA + offA[S + i][0]);
      __builtin_amdgcn_s_setprio(1);
#pragma unroll
      for (int mi = 0; mi < 4; ++mi)
#pragma unroll
        for (int ni = 0; ni < 4; ++ni)
          acc[S + mi][ni] =
              __builtin_amdgcn_mfma_f32_16x16x32_bf16(av[mi], bv[ni], acc[S + mi][ni], 0, 0, 0);
      __builtin_amdgcn_s_setprio(0);
      __builtin_amdgcn_sched_barrier(0);

      // ---- p2: bv(ks1) + av(F half, ks1); MFMA ----
#pragma unroll
      for (int j = 0; j < 4; ++j) bv[j] = *(const bf16x8*)(bufB + offB[j][1]);
#pragma unroll
      for (int i = 0; i < 4; ++i) av[i] = *(const bf16x8*)(bufA + offA[F + i][1]);
      __builtin_amdgcn_s_setprio(1);
#pragma unroll
      for (int mi = 0; mi < 4; ++mi)
#pragma unroll
        for (int ni = 0; ni < 4; ++ni)
          acc[F + mi][ni] =
              __builtin_amdgcn_mfma_f32_16x16x32_bf16(av[mi], bv[ni], acc[F + mi][ni], 0, 0, 0);
      __builtin_amdgcn_s_setprio(0);
      __builtin_amdgcn_sched_barrier(0);

      // ---- p3: av(S half, ks1); MFMA ----
#pragma unroll
      for (int i = 0; i < 4; ++i) av[i] = *(const bf16x8*)(bufA + offA[S + i][1]);
      __builtin_amdgcn_s_setprio(1);
#pragma unroll
      for (int mi = 0; mi < 4; ++mi)
#pragma unroll
        for (int ni = 0; ni < 4; ++ni)
          acc[S + mi][ni] =
              __builtin_amdgcn_mfma_f32_16x16x32_bf16(av[mi], bv[ni], acc[S + mi][ni], 0, 0, 0);
      __builtin_amdgcn_s_setprio(0);
      __builtin_amdgcn_sched_barrier(0);

      // ---- tile end: t+1 (issued at p0, ~3 phases ago) must be resident ----
      if (t < NT - 1) {
        asm volatile("s_waitcnt vmcnt(0)" ::: "memory");
        __builtin_amdgcn_s_barrier();
      }
    }
  };
  if (wave & 1) run_loop(Int<4>{});
  else          run_loop(Int<0>{});

  // ---- fused LSTM epilogue (per-lane: n-frags 0..3 = gates i,f,g,o of h) ---
  const int h = bn * 64 + wn * 16 + lrow;
  const float bi = bpi[h], bf_ = bpf[h], bg = bpg[h], bo = bpo[h];
  const int rbase = bm * BM + wm * 128 + kgrp * 4;
#pragma unroll
  for (int mf = 0; mf < 8; ++mf) {
#pragma unroll
    for (int r = 0; r < 4; ++r) {
      const int brow = rbase + mf * 16 + r;
      float gi = acc[mf][0][r] + bi;
      float gf = acc[mf][1][r] + bf_;
      float gg = acc[mf][2][r] + bg;
      float go = acc[mf][3][r] + bo;
      float i_ = sigm(gi), f_ = sigm(gf), g_ = tanh_fast(gg), o_ = sigm(go);
      float cold = cell[(size_t)brow * H_DIMC + h];
      float cn = f_ * cold + i_ * g_;
      out[(size_t)brow * H_DIMC + h] = o_ * tanh_fast(cn);
      out[(size_t)B_DIM * H_DIMC + (size_t)brow * H_DIMC + h] = cn;
    }
  }
}

extern "C" void kernel_launch(void* const* d_in, const int* in_sizes, int n_in,
                              void* d_out, int out_size, void* d_ws, size_t ws_size,
                              hipStream_t stream) {
  const float* P    = (const float*)d_in[0];
  const float* Hd   = (const float*)d_in[1];
  const float* cell = (const float*)d_in[2];
  const float* X    = (const float*)d_in[3];
  WPtrs w;
  w.pi = (const float*)d_in[4];   const float* bpi = (const float*)d_in[5];
  w.pf = (const float*)d_in[6];   const float* bpf = (const float*)d_in[7];
  w.pg = (const float*)d_in[8];   const float* bpg = (const float*)d_in[9];
  w.po = (const float*)d_in[10];  const float* bpo = (const float*)d_in[11];
  w.hi = (const float*)d_in[12];  w.hf = (const float*)d_in[13];
  w.hg = (const float*)d_in[14];  w.ho = (const float*)d_in[15];
  w.xi = (const float*)d_in[16];  w.xf = (const float*)d_in[17];
  w.xg = (const float*)d_in[18];  w.xo = (const float*)d_in[19];

  unsigned short* Abf = (unsigned short*)d_ws;                 // 32 MiB
  unsigned short* Wbf = Abf + (size_t)B_DIM * K_DIM;           // 64 MiB

  pack_a_kernel<<<2048, 256, 0, stream>>>(P, Hd, X, Abf);
  pack_w_kernel<<<2048, 256, 0, stream>>>(w, Wbf);
  gemm_lstm_kernel<<<512, 512, 0, stream>>>(Abf, Wbf, cell, bpi, bpf, bpg, bpo,
                                            (float*)d_out);
}